// Round 1
// baseline (1171.759 us; speedup 1.0000x reference)
//
#include <hip/hip_runtime.h>
#include <math.h>

// Problem constants (from reference setup_inputs)
constexpr int B  = 16;
constexpr int C  = 256;
constexpr int H  = 128;
constexpr int W  = 128;
constexpr int HW = H * W;          // 16384
constexpr int BC = B * C;          // 4096
constexpr int R  = C / 4;          // 64
constexpr float NEG_SLOPE = 0.01f;

// ws layout (floats): [0,BC)=avg_r [BC,2BC)=avg_i [2BC,3BC)=max_r [3BC,4BC)=max_i
//                     [4BC,5BC)=g_r [5BC,6BC)=g_i
// total 6*4096*4 = 96 KiB

__inline__ __device__ float waveReduceSum(float v) {
#pragma unroll
    for (int o = 32; o > 0; o >>= 1) v += __shfl_down(v, o, 64);
    return v;
}
__inline__ __device__ float waveReduceMax(float v) {
#pragma unroll
    for (int o = 32; o > 0; o >>= 1) v = fmaxf(v, __shfl_down(v, o, 64));
    return v;
}

// One block per (b,c): reduce 16384 floats of x_real and x_imag -> mean & max.
__global__ __launch_bounds__(256) void pool_kernel(
    const float* __restrict__ xr, const float* __restrict__ xi,
    float* __restrict__ ws) {
    const int bc = blockIdx.x;
    const float4* pr = (const float4*)(xr + (size_t)bc * HW);
    const float4* pi = (const float4*)(xi + (size_t)bc * HW);

    float sr = 0.f, si = 0.f;
    float mr = -3.402823466e+38f, mi = -3.402823466e+38f;

#pragma unroll 4
    for (int k = threadIdx.x; k < HW / 4; k += 256) {
        float4 a = pr[k];
        sr += (a.x + a.y) + (a.z + a.w);
        mr = fmaxf(mr, fmaxf(fmaxf(a.x, a.y), fmaxf(a.z, a.w)));
        float4 b = pi[k];
        si += (b.x + b.y) + (b.z + b.w);
        mi = fmaxf(mi, fmaxf(fmaxf(b.x, b.y), fmaxf(b.z, b.w)));
    }

    sr = waveReduceSum(sr);
    si = waveReduceSum(si);
    mr = waveReduceMax(mr);
    mi = waveReduceMax(mi);

    __shared__ float red[4][4];  // [wave][sr,si,mr,mi]
    const int wave = threadIdx.x >> 6;
    const int lane = threadIdx.x & 63;
    if (lane == 0) {
        red[wave][0] = sr; red[wave][1] = si; red[wave][2] = mr; red[wave][3] = mi;
    }
    __syncthreads();
    if (threadIdx.x == 0) {
        float tsr = red[0][0] + red[1][0] + red[2][0] + red[3][0];
        float tsi = red[0][1] + red[1][1] + red[2][1] + red[3][1];
        float tmr = fmaxf(fmaxf(red[0][2], red[1][2]), fmaxf(red[2][2], red[3][2]));
        float tmi = fmaxf(fmaxf(red[0][3], red[1][3]), fmaxf(red[2][3], red[3][3]));
        ws[bc]          = tsr * (1.0f / HW);
        ws[BC + bc]     = tsi * (1.0f / HW);
        ws[2 * BC + bc] = tmr;
        ws[3 * BC + bc] = tmi;
    }
}

// Single block: shared complex MLP on avg and max paths, sum, sigmoid -> gates.
__global__ __launch_bounds__(256) void mlp_kernel(
    const float* __restrict__ ws_pool,  // 4*BC floats: avg_r, avg_i, max_r, max_i
    const float* __restrict__ w1r, const float* __restrict__ w1i,
    const float* __restrict__ b1r, const float* __restrict__ b1i,
    const float* __restrict__ w2r, const float* __restrict__ w2i,
    const float* __restrict__ b2r, const float* __restrict__ b2i,
    float* __restrict__ gr, float* __restrict__ gi) {
    __shared__ float z[4 * BC];          // avg_r, avg_i, max_r, max_i
    __shared__ float h[2][2][B * R];     // [path][re/im][b*R+r]

    const int t = threadIdx.x;
    for (int k = t; k < 4 * BC; k += 256) z[k] = ws_pool[k];
    __syncthreads();

    // Hidden layer: 2 paths * B * R = 2048 complex elements
    for (int item = t; item < 2 * B * R; item += 256) {
        const int p = item / (B * R);
        const int rem = item % (B * R);
        const int b = rem / R;
        const int r = rem % R;
        const float* zr = z + (p * 2 + 0) * BC + b * C;
        const float* zi = z + (p * 2 + 1) * BC + b * C;
        float hr = b1r[r], hi = b1i[r];
        const float* wr_row = w1r + r * C;
        const float* wi_row = w1i + r * C;
#pragma unroll 4
        for (int c = 0; c < C; c++) {
            float wr = wr_row[c], wi = wi_row[c];
            float a = zr[c], bb = zi[c];
            hr += a * wr - bb * wi;
            hi += a * wi + bb * wr;
        }
        hr = hr > 0.f ? hr : NEG_SLOPE * hr;
        hi = hi > 0.f ? hi : NEG_SLOPE * hi;
        h[p][0][b * R + r] = hr;
        h[p][1][b * R + r] = hi;
    }
    __syncthreads();

    // Output layer + sum of paths + sigmoid gate. ar+mr includes b2 twice.
    for (int item = t; item < BC; item += 256) {
        const int b = item / C;
        const int c = item % C;
        float tr = 2.f * b2r[c], ti = 2.f * b2i[c];
        const float* wr_row = w2r + c * R;
        const float* wi_row = w2i + c * R;
#pragma unroll
        for (int p = 0; p < 2; p++) {
            const float* hr = h[p][0] + b * R;
            const float* hi = h[p][1] + b * R;
#pragma unroll 4
            for (int r = 0; r < R; r++) {
                float wr = wr_row[r], wi = wi_row[r];
                float a = hr[r], bb = hi[r];
                tr += a * wr - bb * wi;
                ti += a * wi + bb * wr;
            }
        }
        gr[item] = 1.f / (1.f + expf(-tr));
        gi[item] = 1.f / (1.f + expf(-ti));
    }
}

// Elementwise: out_r = xr*gr - xi*gi ; out_i = xr*gi + xi*gr. One float4/thread.
__global__ __launch_bounds__(256) void gate_kernel(
    const float* __restrict__ xr, const float* __restrict__ xi,
    const float* __restrict__ gr, const float* __restrict__ gi,
    float* __restrict__ outr, float* __restrict__ outi) {
    const int idx = blockIdx.x * 256 + threadIdx.x;   // float4 index, < 2^24
    const int bc = idx >> 12;                          // HW/4 = 4096 = 2^12
    const float g_r = gr[bc];
    const float g_i = gi[bc];
    float4 a = ((const float4*)xr)[idx];
    float4 b = ((const float4*)xi)[idx];
    float4 orv, oiv;
    orv.x = a.x * g_r - b.x * g_i;  oiv.x = a.x * g_i + b.x * g_r;
    orv.y = a.y * g_r - b.y * g_i;  oiv.y = a.y * g_i + b.y * g_r;
    orv.z = a.z * g_r - b.z * g_i;  oiv.z = a.z * g_i + b.z * g_r;
    orv.w = a.w * g_r - b.w * g_i;  oiv.w = a.w * g_i + b.w * g_r;
    ((float4*)outr)[idx] = orv;
    ((float4*)outi)[idx] = oiv;
}

extern "C" void kernel_launch(void* const* d_in, const int* in_sizes, int n_in,
                              void* d_out, int out_size, void* d_ws, size_t ws_size,
                              hipStream_t stream) {
    const float* xr  = (const float*)d_in[0];
    const float* xi  = (const float*)d_in[1];
    const float* w1r = (const float*)d_in[2];
    const float* w1i = (const float*)d_in[3];
    const float* b1r = (const float*)d_in[4];
    const float* b1i = (const float*)d_in[5];
    const float* w2r = (const float*)d_in[6];
    const float* w2i = (const float*)d_in[7];
    const float* b2r = (const float*)d_in[8];
    const float* b2i = (const float*)d_in[9];

    float* ws   = (float*)d_ws;
    float* gr   = ws + 4 * BC;
    float* gi   = ws + 5 * BC;
    float* outr = (float*)d_out;                     // [B,C,H,W]
    float* outi = outr + (size_t)BC * HW;            // [B,C,H,W]

    pool_kernel<<<BC, 256, 0, stream>>>(xr, xi, ws);
    mlp_kernel<<<1, 256, 0, stream>>>(ws, w1r, w1i, b1r, b1i, w2r, w2i, b2r, b2i, gr, gi);
    const int n4 = BC * (HW / 4);                    // 16,777,216 float4 elements
    gate_kernel<<<n4 / 256, 256, 0, stream>>>(xr, xi, gr, gi, outr, outi);
}